// Round 5
// baseline (140.063 us; speedup 1.0000x reference)
//
#include <hip/hip_runtime.h>

// LSTM: IN=2, HID=4, OUT=2, B=8192, T=1024.
// 16 lanes per batch element, GATE-MINOR layout: lane = unit*4 + gate.
//   - quad j (lanes 4j..4j+3) owns hidden unit j; lane's gate = l&3.
//   - gate broadcast within quad: quad_perm 0x00/0x55/0xAA/0xFF (DPP).
//   - h_j is quad-uniform; cross-unit h gather: row_ror:4/8/12 (DPP).
// ALL cross-lane traffic is DPP (VALU latency) — no ds_swizzle/lgkmcnt on
// the recurrence chain (prev version: ~40cy LDS-pipe swizzle on the chain,
// measured 328 cy/step total).
// row_ror:n semantics: dest lane i = src lane (i-n)&15 (data moves toward
// higher lanes, per canonical GCN DPP reduction idiom) -> r_m (ror:4m)
// holds h_{(j-m)&3}; weight arrays permuted accordingly.
// Cell state carried pre-scaled: d = KTC*c, KTC = -2*log2(e). Gate weights
// pre-scaled by -log2(e) (g gate by -2*log2(e)):
//   sigmoid(z) = rcp(1+exp2(zhat)), KTC*tanh(g) = fma(rcp, 2KTC, -KTC).
// 8192*16 = 131072 threads = 2048 waves = 2 waves/SIMD on all 1024 SIMDs.

#define T_LEN 1024
#define NW (T_LEN / 8)

template <int C>
__device__ __forceinline__ float dppf(float v) {
  return __builtin_bit_cast(float,
      __builtin_amdgcn_mov_dpp(__builtin_bit_cast(int, v), C, 0xf, 0xf, true));
}

__global__ __launch_bounds__(256, 2) void lstm_fused(
    const float* __restrict__ x, const float* __restrict__ w_ih,
    const float* __restrict__ w_hh, const float* __restrict__ b_ih,
    const float* __restrict__ b_hh, const float* __restrict__ w_lin,
    const float* __restrict__ b_lin, float* __restrict__ out) {
  const int tid = blockIdx.x * 256 + threadIdx.x;
  const int b = tid >> 4;        // batch element (one per 16-lane group)
  const int l = tid & 15;        // lane within group
  const int gi = l & 3;          // gate index: 0=i 1=f 2=g 3=o
  const int j = (l >> 2) & 3;    // hidden unit = quad index

  const float L2E = 1.4426950408889634f;
  const float KTC = -2.0f * L2E;  // d = KTC * c

  // Per-lane weights for gate gi, unit j (PyTorch row = gi*4 + j).
  const int row = gi * 4 + j;
  const float sc = (gi == 2) ? (-2.0f * L2E) : (-L2E);
  const float wih0 = w_ih[row * 2 + 0] * sc;
  const float wih1 = w_ih[row * 2 + 1] * sc;
  const float bias = (b_ih[row] + b_hh[row]) * sc;
  // r_m (from row_ror:4m) = h_{(j-m)&3}
  const int i1 = (j + 3) & 3, i2 = (j + 2) & 3, i3 = (j + 1) & 3;
  float whh[4];
  whh[0] = w_hh[row * 4 + j] * sc;
  whh[1] = w_hh[row * 4 + i1] * sc;
  whh[2] = w_hh[row * 4 + i2] * sc;
  whh[3] = w_hh[row * 4 + i3] * sc;
  // Post-rcp uniform fma: sigmoid lanes -> val = rcp; g lane -> KTC*tanh(g).
  const float PA = (gi == 2) ? (2.0f * KTC) : 1.0f;
  const float PB = (gi == 2) ? (-KTC) : 0.0f;
  // Output projection (all lanes redundant; parity picks the column).
  const int o = l & 1;
  float wl[4];
  wl[0] = w_lin[o * 4 + j];
  wl[1] = w_lin[o * 4 + i1];
  wl[2] = w_lin[o * 4 + i2];
  wl[3] = w_lin[o * 4 + i3];
  const float blv = b_lin[o];
  const int sl = l >> 1;  // the step this lane stores

  float d = 0.0f;                                   // scaled cell state
  float r0 = 0.0f, r1 = 0.0f, r2 = 0.0f, r3 = 0.0f; // h_{(j-m)&3}

  // x: all 16 lanes of a group load the same float4s (HW broadcast).
  const float4* xq = (const float4*)(x + (size_t)b * (T_LEN * 2));
  float* op = out + (size_t)b * (T_LEN * 2) + l;

  float4 xa0 = xq[0], xa1 = xq[1], xa2 = xq[2], xa3 = xq[3];
  float4 xb0 = xq[4], xb1 = xq[5], xb2 = xq[6], xb3 = xq[7];

  for (int w = 0; w < NW; ++w) {
    const int wn = (w + 2 < NW) ? (w + 2) : w;  // clamped tail prefetch
    const float4* pn = xq + (size_t)wn * 4;
    float4 xc0 = pn[0], xc1 = pn[1], xc2 = pn[2], xc3 = pn[3];

    float keep = 0.0f;

#define STEP(s, X0, X1)                                                    \
  do {                                                                     \
    float ax = fmaf((X1), wih1, fmaf((X0), wih0, bias));                   \
    float t1 = fmaf(r1, whh[1], ax);                                       \
    float t2 = fmaf(r3, whh[3], r2 * whh[2]);                              \
    float t0 = fmaf(r0, whh[0], t1);                                       \
    float a = t0 + t2;                                                     \
    float e = __builtin_amdgcn_exp2f(a);                                   \
    float rr = __builtin_amdgcn_rcpf(1.0f + e);                            \
    float val = fmaf(rr, PA, PB);                                          \
    float si = dppf<0x00>(val); /* quad lane 0 = gate i */                 \
    float sf = dppf<0x55>(val); /* quad lane 1 = gate f */                 \
    float tg = dppf<0xAA>(val); /* quad lane 2 = KTC*tanh(g) */            \
    float so = dppf<0xFF>(val); /* quad lane 3 = gate o */                 \
    d = fmaf(sf, d, si * tg);                                              \
    float ec = __builtin_amdgcn_exp2f(d);                                  \
    float rc = __builtin_amdgcn_rcpf(1.0f + ec);                           \
    float h = fmaf(so + so, rc, -so); /* = so*tanh(c), quad-uniform */     \
    r0 = h;                                                                \
    r1 = dppf<0x124>(h); /* row_ror:4  -> h_{(j-1)&3} */                   \
    r2 = dppf<0x128>(h); /* row_ror:8  -> h_{(j-2)&3} */                   \
    r3 = dppf<0x12C>(h); /* row_ror:12 -> h_{(j-3)&3} */                   \
    float ov = fmaf(r3, wl[3], fmaf(r2, wl[2],                             \
                    fmaf(r1, wl[1], fmaf(r0, wl[0], blv))));               \
    if (sl == (s)) keep = ov;                                              \
  } while (0)

    STEP(0, xa0.x, xa0.y); STEP(1, xa0.z, xa0.w);
    STEP(2, xa1.x, xa1.y); STEP(3, xa1.z, xa1.w);
    STEP(4, xa2.x, xa2.y); STEP(5, xa2.z, xa2.w);
    STEP(6, xa3.x, xa3.y); STEP(7, xa3.z, xa3.w);
#undef STEP

    // Lane l stores out[b, w*8 + l/2, l&1] = flat b*2048 + w*16 + l.
    op[w * 16] = keep;

    xa0 = xb0; xa1 = xb1; xa2 = xb2; xa3 = xb3;
    xb0 = xc0; xb1 = xc1; xb2 = xc2; xb3 = xc3;
  }
}

extern "C" void kernel_launch(void* const* d_in, const int* in_sizes, int n_in,
                              void* d_out, int out_size, void* d_ws, size_t ws_size,
                              hipStream_t stream) {
  const float* x     = (const float*)d_in[0];
  const float* w_ih  = (const float*)d_in[1];
  const float* w_hh  = (const float*)d_in[2];
  const float* b_ih  = (const float*)d_in[3];
  const float* b_hh  = (const float*)d_in[4];
  const float* w_lin = (const float*)d_in[5];
  const float* b_lin = (const float*)d_in[6];
  float* out = (float*)d_out;

  // 8192 groups * 16 lanes = 131072 threads = 2048 waves (2 per SIMD).
  lstm_fused<<<512, 256, 0, stream>>>(x, w_ih, w_hh, b_ih, b_hh, w_lin, b_lin, out);
}